// Round 7
// baseline (189.224 us; speedup 1.0000x reference)
//
#include <hip/hip_runtime.h>

// Problem constants (fixed by the reference): N=262144, D=256, B=512, M=1024.
#define FEAT_D   256
#define MAX_M    1024
#define NSETS    512

typedef float f4 __attribute__((ext_vector_type(4)));
typedef float f2 __attribute__((ext_vector_type(2)));

// Fully fused: no k_starts prologue kernel. Each wave handles 2 consecutive
// output rows (same set: blocks cover 8 consecutive rows, 1024 % 8 == 0, so
// the set id b is block-uniform). The wave finds its set's (start,count) by
// two INTERLEAVED scalar binary searches over the sorted batch array
// (b is SGPR after readfirstlane -> s_load chain, 2 independent searches in
// flight, 18 iterations). batch is 1MB -> L2-resident; the redundant
// per-block searches hide under the streaming pipeline of other blocks.
// Main stream identical to R6 (best so far): per lane one float4 of each of
// 2 rows, nt loads + nt stores, mask as one f2 store per wave from lane 0.
__global__ void __launch_bounds__(256)
k_fused(const int* __restrict__ batch, int n,
        const f4* __restrict__ src4,
        f4* __restrict__ out4,
        f2* __restrict__ mask2) {
    int tid  = blockIdx.x * blockDim.x + threadIdx.x;
    int pair = tid >> 6;              // wave id = pair of rows
    int lane = tid & 63;
    int row0 = pair << 1;             // first of the 2 rows
    int b = __builtin_amdgcn_readfirstlane(row0 >> 10);

    // lower_bound(b) and lower_bound(b+1), interleaved (both take the same
    // iteration count from range [0,n), so one loop drives both chains).
    int lo0 = 0, hi0 = n, lo1 = 0, hi1 = n;
    while (lo0 < hi0) {
        int m0 = (lo0 + hi0) >> 1;
        int m1 = (lo1 + hi1) >> 1;
        int v0 = batch[m0];           // SGPR address -> s_load
        int v1 = batch[m1];
        if (v0 < b)     lo0 = m0 + 1; else hi0 = m0;
        if (v1 < b + 1) lo1 = m1 + 1; else hi1 = m1;
    }
    int s = lo0, cnt = lo1 - lo0;

    int m0 = row0 & (MAX_M - 1);
    bool v0 = (m0 < cnt), v1 = (m0 + 1 < cnt);   // wave-uniform
    f4 a0 = (f4)(0.0f), a1 = (f4)(0.0f);
    const f4* ip = src4 + ((size_t)s + m0) * (FEAT_D / 4) + lane;
    if (v0) a0 = __builtin_nontemporal_load(ip);
    if (v1) a1 = __builtin_nontemporal_load(ip + (FEAT_D / 4));
    f4* op = out4 + (size_t)row0 * (FEAT_D / 4) + lane;
    __builtin_nontemporal_store(a0, op);
    __builtin_nontemporal_store(a1, op + (FEAT_D / 4));
    if (lane == 0) {
        f2 mv;
        mv[0] = v0 ? 1.0f : 0.0f;
        mv[1] = v1 ? 1.0f : 0.0f;
        __builtin_nontemporal_store(mv, &mask2[pair]);
    }
}

extern "C" void kernel_launch(void* const* d_in, const int* in_sizes, int n_in,
                              void* d_out, int out_size, void* d_ws, size_t ws_size,
                              hipStream_t stream) {
    const float* src   = (const float*)d_in[0];
    const int*   batch = (const int*)d_in[1];   // harness delivers ints as int32
    int n = in_sizes[1];                        // N ragged elements

    int total_rows = NSETS * MAX_M;             // 524288
    f2* mask2 = (f2*)((float*)d_out + (size_t)NSETS * MAX_M * FEAT_D);
    k_fused<<<total_rows / 8, 256, 0, stream>>>(
        batch, n, (const f4*)src, (f4*)d_out, mask2);
}

// Round 8
// 149.457 us; speedup vs baseline: 1.2661x; 1.2661x over previous
//
#include <hip/hip_runtime.h>

// Problem constants (fixed by the reference): N=262144, D=256, B=512, M=1024.
#define FEAT_D   256
#define MAX_M    1024
#define NSETS    512

typedef float f4 __attribute__((ext_vector_type(4)));
typedef float f2 __attribute__((ext_vector_type(2)));

// sc[b] = (start, count) for set b via two binary searches (batch sorted).
__global__ void k_starts(const int* __restrict__ batch, int n,
                         int2* __restrict__ sc) {
    int b = blockIdx.x * blockDim.x + threadIdx.x;
    if (b >= NSETS) return;
    int lo = 0, hi = n;
    while (lo < hi) { int mid = (lo + hi) >> 1; if (batch[mid] < b) lo = mid + 1; else hi = mid; }
    int lo2 = lo, hi2 = n;      // lower_bound(b+1), search range [lo, n)
    while (lo2 < hi2) { int mid = (lo2 + hi2) >> 1; if (batch[mid] < b + 1) lo2 = mid + 1; else hi2 = mid; }
    sc[b] = make_int2(lo, lo2 - lo);
}

// Best configuration (R6, 148.8us — all A/B'd):
//  - one-shot stream: each wave owns 2 consecutive rows, lane l moves float4
//    #l of each row (64 lanes * 16B = one full 1KB row, perfectly coalesced);
//    2 independent nt loads in flight, then 2 nt stores. Deeper per-wave work
//    (R3: 64 rows looped) and fused per-wave binary search (R7) both regress
//    by serializing ahead of the stream.
//  - (start,count) fetched once per block via readfirstlane -> scalar load
//    (b is block-uniform: blocks cover 8 consecutive rows, 1024 % 8 == 0).
//  - nt on BOTH loads and stores (R2 nt/nt 150.7 beat R1 plain/plain 155.9
//    and R4 nt/plain 158.4): zero-reuse streams must bypass L2/L3.
__global__ void __launch_bounds__(256)
k_gather(const f4* __restrict__ src4,
         const int2* __restrict__ sc,
         f4* __restrict__ out4,
         f2* __restrict__ mask2) {
    int tid  = blockIdx.x * blockDim.x + threadIdx.x;
    int pair = tid >> 6;              // wave id = pair of rows
    int lane = tid & 63;
    int row0 = pair << 1;             // first of the 2 rows
    int b = __builtin_amdgcn_readfirstlane(row0 >> 10);
    int2 s_c = sc[b];                 // uniform address -> s_load
    int s = s_c.x, cnt = s_c.y;
    int m0 = row0 & (MAX_M - 1);
    bool v0 = (m0 < cnt), v1 = (m0 + 1 < cnt);   // wave-uniform
    f4 a0 = (f4)(0.0f), a1 = (f4)(0.0f);
    const f4* ip = src4 + ((size_t)s + m0) * (FEAT_D / 4) + lane;
    if (v0) a0 = __builtin_nontemporal_load(ip);
    if (v1) a1 = __builtin_nontemporal_load(ip + (FEAT_D / 4));
    f4* op = out4 + (size_t)row0 * (FEAT_D / 4) + lane;
    __builtin_nontemporal_store(a0, op);
    __builtin_nontemporal_store(a1, op + (FEAT_D / 4));
    if (lane == 0) {
        f2 mv;
        mv[0] = v0 ? 1.0f : 0.0f;
        mv[1] = v1 ? 1.0f : 0.0f;
        __builtin_nontemporal_store(mv, &mask2[pair]);
    }
}

extern "C" void kernel_launch(void* const* d_in, const int* in_sizes, int n_in,
                              void* d_out, int out_size, void* d_ws, size_t ws_size,
                              hipStream_t stream) {
    const float* src   = (const float*)d_in[0];
    const int*   batch = (const int*)d_in[1];   // harness delivers ints as int32
    int n = in_sizes[1];                        // N ragged elements

    int2* sc = (int2*)d_ws;                     // NSETS (start,count) pairs

    // 1) segment (start,count) via binary search (512 threads, trivial cost)
    k_starts<<<(NSETS + 255) / 256, 256, 0, stream>>>(batch, n, sc);

    // 2) padded gather + fused mask: 2 rows per wave, 8 rows per block
    int total_rows = NSETS * MAX_M;             // 524288
    f2* mask2 = (f2*)((float*)d_out + (size_t)NSETS * MAX_M * FEAT_D);
    k_gather<<<total_rows / 8, 256, 0, stream>>>(
        (const f4*)src, sc, (f4*)d_out, mask2);
}